// Round 3
// baseline (592.335 us; speedup 1.0000x reference)
//
#include <hip/hip_runtime.h>
#include <stdint.h>

#define B_ 64
#define C_ 4
#define R_ 64
#define E_ 512
#define P_ 4
#define OS_ 256
#define L_ (R_*E_)        // 32768
#define K_ (L_*P_)        // 131072
#define M_ (B_*C_)        // 256

#define BM 128
#define BN 128
#define BK 32
#define ZSPLIT 512        // K-chunk = 256, 8 iters/block, 2048 blocks

typedef float  floatx4 __attribute__((ext_vector_type(4)));
typedef short  shortx8 __attribute__((ext_vector_type(8)));

static __device__ __forceinline__ unsigned short f2bf(float f) {
  union { float f; unsigned int u; } v; v.f = f;
  unsigned int u = v.u;
  u += 0x7fffu + ((u >> 16) & 1u);   // RNE
  return (unsigned short)(u >> 16);
}

// LDS tile granule index (16-B granules). Swizzle keeps both staging writes
// and fragment reads at <=2-way bank aliasing (free per m136).
static __device__ __forceinline__ int gidx(int row, int ch) {
  return (row >> 4) * 64 + ch * 16 + ((row & 15) ^ (ch << 2));
}

// One block per (bc, r): stage x-row in LDS (1 barrier), gather+sign, pool
// via in-wave shuffle tournaments (k<=8 fits in a wave), coalesced bf16 stores.
__global__ __launch_bounds__(512) void build_A(
    const float* __restrict__ x, const int* __restrict__ rxd_perm,
    const int* __restrict__ e_idx, const float* __restrict__ signs,
    unsigned short* __restrict__ A) {
  const int bcr = blockIdx.x;          // 16384 = 256 bc * 64 r
  const int r  = bcr & (R_ - 1);
  const int bc = bcr >> 6;
  const int e  = threadIdx.x;          // 0..511
  __shared__ float xr[E_];
  xr[e] = x[((size_t)(bc * R_ + rxd_perm[r])) * E_ + e];
  __syncthreads();

  const uint4  ei = *(const uint4*)(e_idx + e * 4);
  const float4 sg = *(const float4*)(signs + e * 4);
  const float v0 = xr[ei.x] * sg.x;
  const float v1 = xr[ei.y] * sg.y;
  const float v2 = xr[ei.z] * sg.z;
  const float v3 = xr[ei.w] * sg.w;

  unsigned short* dst = A + (size_t)bc * K_ + r * E_ + e;
  dst[0] = f2bf(v0);

  // p=1 (k=2): keep iff this lane is the first argmax of its pair
  {
    const float ov = __shfl_xor(v1, 1, 64);
    const bool keep = (e & 1) ? (v1 > ov) : (v1 >= ov);
    dst[L_] = f2bf(keep ? v1 : 0.0f);
  }
  // p=2 (k=4): (value, index) tournament, first-max tie-break
  {
    float m = v2; int mi = e;
    #pragma unroll
    for (int d = 1; d <= 2; d <<= 1) {
      const float om  = __shfl_xor(m, d, 64);
      const int   omi = __shfl_xor(mi, d, 64);
      const bool take = (om > m) || (om == m && omi < mi);
      m = take ? om : m; mi = take ? omi : mi;
    }
    dst[2 * L_] = f2bf((mi == e) ? v2 : 0.0f);
  }
  // p=3 (k=8)
  {
    float m = v3; int mi = e;
    #pragma unroll
    for (int d = 1; d <= 4; d <<= 1) {
      const float om  = __shfl_xor(m, d, 64);
      const int   omi = __shfl_xor(mi, d, 64);
      const bool take = (om > m) || (om == m && omi < mi);
      m = take ? om : m; mi = take ? omi : mi;
    }
    dst[3 * L_] = f2bf((mi == e) ? v3 : 0.0f);
  }
}

__global__ void init_out(const float* __restrict__ bias, float* __restrict__ out) {
  const int i = blockIdx.x * blockDim.x + threadIdx.x;
  out[i] = bias[i & (OS_ - 1)];
}

// Split-K GEMM, atomic fp32 accumulate into bias-initialized out.
// 8 blocks/CU (16 KB LDS, VGPR<=64) so co-resident blocks cover each
// other's barrier drains.
__global__ __launch_bounds__(256, 8) void gemm_splitk(
    const unsigned short* __restrict__ A, const float* __restrict__ W,
    float* __restrict__ out, int kch) {
  __shared__ unsigned short As[BM * BK];   // 8 KB, swizzled granules
  __shared__ unsigned short Ws[BN * BK];   // 8 KB (bf16-converted at stage)
  const int t    = threadIdx.x;
  const int lane = t & 63;
  const int wv   = t >> 6;
  const int mBase = blockIdx.x * BM;
  const int nBase = blockIdx.y * BN;
  const size_t k0base = (size_t)blockIdx.z * kch;

  const int wm   = (wv >> 1) * 64;
  const int wn   = (wv & 1) * 64;
  const int lrow = lane & 15;
  const int quad = lane >> 4;
  const int srow = t >> 2;       // staging: 4 lanes per row
  const int sch  = t & 3;

  floatx4 acc[4][4];
  #pragma unroll
  for (int i = 0; i < 4; ++i)
    #pragma unroll
    for (int j = 0; j < 4; ++j)
      acc[i][j] = {0.f, 0.f, 0.f, 0.f};

  for (int kk = 0; kk < kch; kk += BK) {
    const size_t k0 = k0base + kk;
    // stage A: 128 rows x 32 bf16, 2 rounds x 256 thr x 16 B
    #pragma unroll
    for (int i = 0; i < 2; ++i) {
      const int rr = srow + i * 64;
      const uint4 d = *(const uint4*)(A + (size_t)(mBase + rr) * K_ + k0 + sch * 8);
      *(uint4*)(As + gidx(rr, sch) * 8) = d;
    }
    // stage W: 128 rows x 32 f32 -> bf16, 2 rounds x 256 thr
    #pragma unroll
    for (int i = 0; i < 2; ++i) {
      const int rr = srow + i * 64;
      const float* wp = W + (size_t)(nBase + rr) * K_ + k0 + sch * 8;
      const float4 a0 = *(const float4*)(wp);
      const float4 a1 = *(const float4*)(wp + 4);
      shortx8 bfv;
      bfv[0] = (short)f2bf(a0.x); bfv[1] = (short)f2bf(a0.y);
      bfv[2] = (short)f2bf(a0.z); bfv[3] = (short)f2bf(a0.w);
      bfv[4] = (short)f2bf(a1.x); bfv[5] = (short)f2bf(a1.y);
      bfv[6] = (short)f2bf(a1.z); bfv[7] = (short)f2bf(a1.w);
      *(shortx8*)(Ws + gidx(rr, sch) * 8) = bfv;
    }
    __syncthreads();

    shortx8 af[4], wf[4];
    const int fofs = quad * 16 + (lrow ^ (quad << 2));
    #pragma unroll
    for (int ti = 0; ti < 4; ++ti)
      af[ti] = *(const shortx8*)(As + (((wm >> 4) + ti) * 64 + fofs) * 8);
    #pragma unroll
    for (int tj = 0; tj < 4; ++tj)
      wf[tj] = *(const shortx8*)(Ws + (((wn >> 4) + tj) * 64 + fofs) * 8);

    #pragma unroll
    for (int ti = 0; ti < 4; ++ti)
      #pragma unroll
      for (int tj = 0; tj < 4; ++tj)
        acc[ti][tj] = __builtin_amdgcn_mfma_f32_16x16x32_bf16(af[ti], wf[tj], acc[ti][tj], 0, 0, 0);
    __syncthreads();
  }

  // epilogue (D layout: m = quad*4+reg, n = lane&15)
  #pragma unroll
  for (int ti = 0; ti < 4; ++ti)
    #pragma unroll
    for (int tj = 0; tj < 4; ++tj)
      #pragma unroll
      for (int j = 0; j < 4; ++j) {
        const int m = mBase + wm + ti * 16 + quad * 4 + j;
        const int n = nBase + wn + tj * 16 + lrow;
        atomicAdd(out + (size_t)m * OS_ + n, acc[ti][tj][j]);
      }
}

extern "C" void kernel_launch(void* const* d_in, const int* in_sizes, int n_in,
                              void* d_out, int out_size, void* d_ws, size_t ws_size,
                              hipStream_t stream) {
  const float* x        = (const float*)d_in[0];
  const int*   rxd_perm = (const int*)d_in[1];
  const int*   e_idx    = (const int*)d_in[2];
  const float* signs    = (const float*)d_in[3];
  const float* W        = (const float*)d_in[4];
  const float* bias     = (const float*)d_in[5];
  float* out = (float*)d_out;

  unsigned short* A = (unsigned short*)d_ws;   // 256 x 131072 bf16 = 67.1 MB

  build_A<<<dim3(B_ * C_ * R_), dim3(512), 0, stream>>>(x, rxd_perm, e_idx, signs, A);
  init_out<<<dim3((OS_ * M_) / 256), dim3(256), 0, stream>>>(bias, out);
  gemm_splitk<<<dim3(M_ / BM, OS_ / BN, ZSPLIT), dim3(256), 0, stream>>>(A, W, out, K_ / ZSPLIT);
}

// Round 5
// 312.761 us; speedup vs baseline: 1.8939x; 1.8939x over previous
//
#include <hip/hip_runtime.h>
#include <stdint.h>

#define B_ 64
#define C_ 4
#define R_ 64
#define E_ 512
#define P_ 4
#define OS_ 256
#define L_ (R_*E_)        // 32768
#define K_ (L_*P_)        // 131072
#define M_ (B_*C_)        // 256

#define BM 128
#define BN 64
#define BK 32
#define ZZ 256            // K-split -> grid (2,4,256) = 2048 blocks = 8/CU
#define KCH (K_/ZZ)       // 512 -> 16 k-iters per block

typedef float  floatx4 __attribute__((ext_vector_type(4)));
typedef short  shortx8 __attribute__((ext_vector_type(8)));

static __device__ __forceinline__ unsigned short f2bf(float f) {
  union { float f; unsigned int u; } v; v.f = f;
  unsigned int u = v.u;
  u += 0x7fffu + ((u >> 16) & 1u);   // RNE
  return (unsigned short)(u >> 16);
}

// LDS tile granule index (16-B granules); <=2-way bank aliasing on both the
// staging writes and the quad-phased fragment reads (free per m136).
static __device__ __forceinline__ int gidx(int row, int ch) {
  return (row >> 4) * 64 + ch * 16 + ((row & 15) ^ (ch << 2));
}

// One block per (bc, r): stage x-row in LDS (1 barrier), gather+sign, pool
// via in-wave shuffle tournaments (k<=8 fits in a wave), coalesced bf16 stores.
__global__ __launch_bounds__(512) void build_A(
    const float* __restrict__ x, const int* __restrict__ rxd_perm,
    const int* __restrict__ e_idx, const float* __restrict__ signs,
    unsigned short* __restrict__ A) {
  const int bcr = blockIdx.x;          // 16384 = 256 bc * 64 r
  const int r  = bcr & (R_ - 1);
  const int bc = bcr >> 6;
  const int e  = threadIdx.x;          // 0..511
  __shared__ float xr[E_];
  xr[e] = x[((size_t)(bc * R_ + rxd_perm[r])) * E_ + e];
  __syncthreads();

  const uint4  ei = *(const uint4*)(e_idx + e * 4);
  const float4 sg = *(const float4*)(signs + e * 4);
  const float v0 = xr[ei.x] * sg.x;
  const float v1 = xr[ei.y] * sg.y;
  const float v2 = xr[ei.z] * sg.z;
  const float v3 = xr[ei.w] * sg.w;

  unsigned short* dst = A + (size_t)bc * K_ + r * E_ + e;
  dst[0] = f2bf(v0);

  // p=1 (k=2): keep iff this lane is the first argmax of its pair
  {
    const float ov = __shfl_xor(v1, 1, 64);
    const bool keep = (e & 1) ? (v1 > ov) : (v1 >= ov);
    dst[L_] = f2bf(keep ? v1 : 0.0f);
  }
  // p=2 (k=4): (value, index) tournament, first-max tie-break
  {
    float m = v2; int mi = e;
    #pragma unroll
    for (int d = 1; d <= 2; d <<= 1) {
      const float om  = __shfl_xor(m, d, 64);
      const int   omi = __shfl_xor(mi, d, 64);
      const bool take = (om > m) || (om == m && omi < mi);
      m = take ? om : m; mi = take ? omi : mi;
    }
    dst[2 * L_] = f2bf((mi == e) ? v2 : 0.0f);
  }
  // p=3 (k=8)
  {
    float m = v3; int mi = e;
    #pragma unroll
    for (int d = 1; d <= 4; d <<= 1) {
      const float om  = __shfl_xor(m, d, 64);
      const int   omi = __shfl_xor(mi, d, 64);
      const bool take = (om > m) || (om == m && omi < mi);
      m = take ? om : m; mi = take ? omi : mi;
    }
    dst[3 * L_] = f2bf((mi == e) ? v3 : 0.0f);
  }
}

// Split-K GEMM, round-2-proven two-barrier loop, tile 128x64, z=256.
// Non-atomic per-z partials. 8 blocks/CU target (12 KB LDS, VGPR ~50).
__global__ __launch_bounds__(256, 4) void gemm_splitk(
    const unsigned short* __restrict__ A, const float* __restrict__ W,
    float* __restrict__ Ppart) {
  __shared__ unsigned short As[BM * BK];   // 8 KB, swizzled granules
  __shared__ unsigned short Ws[BN * BK];   // 4 KB (bf16-converted at stage)
  const int t    = threadIdx.x;
  const int lane = t & 63;
  const int wv   = t >> 6;                 // 0..3
  const int mBase = blockIdx.x * BM;
  const int nBase = blockIdx.y * BN;
  const size_t k0base = (size_t)blockIdx.z * KCH;

  const int wm   = (wv >> 1) * 64;         // 0,64
  const int wn   = (wv & 1) * 32;          // 0,32
  const int lrow = lane & 15;
  const int quad = lane >> 4;
  const int srow = t >> 2;                 // staging: 4 lanes per row
  const int sch  = t & 3;

  floatx4 acc[4][2];
  #pragma unroll
  for (int i = 0; i < 4; ++i)
    #pragma unroll
    for (int j = 0; j < 2; ++j)
      acc[i][j] = {0.f, 0.f, 0.f, 0.f};

  for (int kk = 0; kk < KCH; kk += BK) {
    const size_t k0 = k0base + kk;
    // stage A: 128 rows x 32 bf16, 2 rounds x 256 thr x 16 B
    #pragma unroll
    for (int i = 0; i < 2; ++i) {
      const int rr = srow + i * 64;
      const uint4 d = *(const uint4*)(A + (size_t)(mBase + rr) * K_ + k0 + sch * 8);
      *(uint4*)(As + gidx(rr, sch) * 8) = d;
    }
    // stage W: 64 rows x 32 f32 -> bf16, 1 round x 256 thr
    {
      const float* wp = W + (size_t)(nBase + srow) * K_ + k0 + sch * 8;
      const float4 a0 = *(const float4*)(wp);
      const float4 a1 = *(const float4*)(wp + 4);
      shortx8 bfv;
      bfv[0] = (short)f2bf(a0.x); bfv[1] = (short)f2bf(a0.y);
      bfv[2] = (short)f2bf(a0.z); bfv[3] = (short)f2bf(a0.w);
      bfv[4] = (short)f2bf(a1.x); bfv[5] = (short)f2bf(a1.y);
      bfv[6] = (short)f2bf(a1.z); bfv[7] = (short)f2bf(a1.w);
      *(shortx8*)(Ws + gidx(srow, sch) * 8) = bfv;
    }
    __syncthreads();

    shortx8 af[4], wf[2];
    const int fofs = quad * 16 + (lrow ^ (quad << 2));
    #pragma unroll
    for (int ti = 0; ti < 4; ++ti)
      af[ti] = *(const shortx8*)(As + (((wm >> 4) + ti) * 64 + fofs) * 8);
    #pragma unroll
    for (int tj = 0; tj < 2; ++tj)
      wf[tj] = *(const shortx8*)(Ws + (((wn >> 4) + tj) * 64 + fofs) * 8);

    #pragma unroll
    for (int ti = 0; ti < 4; ++ti)
      #pragma unroll
      for (int tj = 0; tj < 2; ++tj)
        acc[ti][tj] = __builtin_amdgcn_mfma_f32_16x16x32_bf16(af[ti], wf[tj], acc[ti][tj], 0, 0, 0);
    __syncthreads();
  }

  // epilogue: per-z partial tile (D layout: m = quad*4+reg, n = lane&15)
  float* dst = Ppart + (size_t)blockIdx.z * (M_ * OS_);
  #pragma unroll
  for (int ti = 0; ti < 4; ++ti)
    #pragma unroll
    for (int tj = 0; tj < 2; ++tj)
      #pragma unroll
      for (int j = 0; j < 4; ++j) {
        const int m = mBase + wm + ti * 16 + quad * 4 + j;
        const int n = nBase + wn + tj * 16 + lrow;
        dst[(size_t)m * OS_ + n] = acc[ti][tj][j];
      }
}

// out[m][n] = bias[n] + sum_z P[z][m][n]; 256 blocks x 64 thr = all CUs busy
__global__ __launch_bounds__(64) void reduce_out(
    const float* __restrict__ P, const float* __restrict__ bias,
    float* __restrict__ out) {
  const int tid = blockIdx.x * 64 + threadIdx.x;   // 16384
  const int n4 = (tid & 63) * 4;
  const int m  = tid >> 6;
  floatx4 s = *(const floatx4*)(bias + n4);
  const float* p = P + (size_t)m * OS_ + n4;
  #pragma unroll 8
  for (int z = 0; z < ZZ; ++z)
    s += *(const floatx4*)(p + (size_t)z * (M_ * OS_));
  *(floatx4*)(out + (size_t)m * OS_ + n4) = s;
}

extern "C" void kernel_launch(void* const* d_in, const int* in_sizes, int n_in,
                              void* d_out, int out_size, void* d_ws, size_t ws_size,
                              hipStream_t stream) {
  const float* x        = (const float*)d_in[0];
  const int*   rxd_perm = (const int*)d_in[1];
  const int*   e_idx    = (const int*)d_in[2];
  const float* signs    = (const float*)d_in[3];
  const float* W        = (const float*)d_in[4];
  const float* bias     = (const float*)d_in[5];
  float* out = (float*)d_out;

  unsigned short* A = (unsigned short*)d_ws;            // 67.1 MB
  const size_t A_BYTES = (size_t)M_ * K_ * 2;
  float* Ppart = (float*)((char*)d_ws + A_BYTES);       // 256 * 256KB = 67.1 MB

  build_A<<<dim3(B_ * C_ * R_), dim3(512), 0, stream>>>(x, rxd_perm, e_idx, signs, A);
  gemm_splitk<<<dim3(M_ / BM, OS_ / BN, ZZ), dim3(256), 0, stream>>>(A, W, Ppart);
  reduce_out<<<dim3(256), dim3(64), 0, stream>>>(Ppart, bias, out);
}

// Round 6
// 298.463 us; speedup vs baseline: 1.9846x; 1.0479x over previous
//
#include <hip/hip_runtime.h>
#include <stdint.h>

#define B_ 64
#define C_ 4
#define R_ 64
#define E_ 512
#define P_ 4
#define OS_ 256
#define L_ (R_*E_)        // 32768
#define K_ (L_*P_)        // 131072
#define M_ (B_*C_)        // 256

#define BM 256            // grid.x = 1 -> W streamed exactly once
#define BN 128
#define BK 64
#define ZZ 256            // grid (1,2,256) = 512 blocks = 2/CU
#define KCH (K_/ZZ)       // 512 -> 8 fat k-iters per block

typedef float  floatx4 __attribute__((ext_vector_type(4)));
typedef short  shortx8 __attribute__((ext_vector_type(8)));

// async global->LDS, 16 B per lane; LDS dest is wave-uniform base + lane*16
#define GLDS16(g, l) __builtin_amdgcn_global_load_lds(                      \
    (const __attribute__((address_space(1))) void*)(g),                     \
    (__attribute__((address_space(3))) void*)(l), 16, 0, 0)

static __device__ __forceinline__ unsigned short f2bf(float f) {
  union { float f; unsigned int u; } v; v.f = f;
  unsigned int u = v.u;
  u += 0x7fffu + ((u >> 16) & 1u);   // RNE
  return (unsigned short)(u >> 16);
}

// One block per (bc, r): stage x-row in LDS (1 barrier), gather+sign, pool
// via in-wave shuffle tournaments (k<=8 fits in a wave), coalesced bf16 stores.
__global__ __launch_bounds__(512) void build_A(
    const float* __restrict__ x, const int* __restrict__ rxd_perm,
    const int* __restrict__ e_idx, const float* __restrict__ signs,
    unsigned short* __restrict__ A) {
  const int bcr = blockIdx.x;          // 16384 = 256 bc * 64 r
  const int r  = bcr & (R_ - 1);
  const int bc = bcr >> 6;
  const int e  = threadIdx.x;          // 0..511
  __shared__ float xr[E_];
  xr[e] = x[((size_t)(bc * R_ + rxd_perm[r])) * E_ + e];
  __syncthreads();

  const uint4  ei = *(const uint4*)(e_idx + e * 4);
  const float4 sg = *(const float4*)(signs + e * 4);
  const float v0 = xr[ei.x] * sg.x;
  const float v1 = xr[ei.y] * sg.y;
  const float v2 = xr[ei.z] * sg.z;
  const float v3 = xr[ei.w] * sg.w;

  unsigned short* dst = A + (size_t)bc * K_ + r * E_ + e;
  dst[0] = f2bf(v0);

  {  // p=1 (k=2): keep iff first argmax of the pair
    const float ov = __shfl_xor(v1, 1, 64);
    const bool keep = (e & 1) ? (v1 > ov) : (v1 >= ov);
    dst[L_] = f2bf(keep ? v1 : 0.0f);
  }
  {  // p=2 (k=4)
    float m = v2; int mi = e;
    #pragma unroll
    for (int d = 1; d <= 2; d <<= 1) {
      const float om  = __shfl_xor(m, d, 64);
      const int   omi = __shfl_xor(mi, d, 64);
      const bool take = (om > m) || (om == m && omi < mi);
      m = take ? om : m; mi = take ? omi : mi;
    }
    dst[2 * L_] = f2bf((mi == e) ? v2 : 0.0f);
  }
  {  // p=3 (k=8)
    float m = v3; int mi = e;
    #pragma unroll
    for (int d = 1; d <= 4; d <<= 1) {
      const float om  = __shfl_xor(m, d, 64);
      const int   omi = __shfl_xor(mi, d, 64);
      const bool take = (om > m) || (om == m && omi < mi);
      m = take ? om : m; mi = take ? omi : mi;
    }
    dst[3 * L_] = f2bf((mi == e) ? v3 : 0.0f);
  }
}

__global__ void init_out(const float* __restrict__ bias, float* __restrict__ out) {
  const int i = blockIdx.x * blockDim.x + threadIdx.x;
  out[i] = bias[i & (OS_ - 1)];
}

// Split-K GEMM: tile 256x128, BK=64, A staged via global_load_lds (async,
// zero staging VGPRs), W staged f32->bf16 via VGPR. Two-barrier proven loop.
// Atomic fp32 accumulate into bias-initialized out.
// LDS granule slot = row*8 + (ch ^ (row&7)): lane-linear invertible (GLDS
// requirement) and <=2-way bank aliasing for staging writes AND b128 reads.
__global__ __launch_bounds__(512, 4) void gemm_splitk(
    const unsigned short* __restrict__ A, const float* __restrict__ W,
    float* __restrict__ out) {
  __shared__ unsigned short As[BM * BK];   // 32 KB
  __shared__ unsigned short Ws[BN * BK];   // 16 KB (bf16 at stage)
  const int t    = threadIdx.x;
  const int lane = t & 63;
  const int wv   = t >> 6;                 // 0..7

  // XCD pair swizzle: ids i and i+8 share z -> same XCD (round-robin heuristic)
  const int id = blockIdx.x;               // 0..511
  const int ny = (id >> 3) & 1;
  const int z  = (id & 7) | ((id >> 4) << 3);
  const int nBase = ny * BN;
  const size_t k0base = (size_t)z * KCH;

  const int wm   = (wv >> 1) * 64;         // 0,64,128,192
  const int wn   = (wv & 1) * 64;          // 0,64
  const int lrow = lane & 15;
  const int quad = lane >> 4;
  const int rx   = lrow & 7;               // row&7 for fragment rows

  // A staging via GLDS: wave w, call c in 0..3; slot block = (w*4+c)*64 + lane
  // inverse swizzle: row = slot>>3, ch = (slot&7) ^ (row&7)
  const int aCh = (lane & 7) ^ ((lane >> 3) & 7);
  // W staging: 2 passes, granule q = pass*512 + t: row=q>>3, ch=q&7
  floatx4 acc[4][4];
  #pragma unroll
  for (int i = 0; i < 4; ++i)
    #pragma unroll
    for (int j = 0; j < 4; ++j)
      acc[i][j] = {0.f, 0.f, 0.f, 0.f};

  for (int it = 0; it < (KCH / BK); ++it) {
    const size_t k0 = k0base + (size_t)it * BK;
    // --- stage A: 256 rows x 64 bf16 = 2048 granules, 4 GLDS calls/wave ---
    #pragma unroll
    for (int c = 0; c < 4; ++c) {
      const int sblk = (wv * 4 + c) * 64;            // granule slot base
      const int row  = (sblk >> 3) + (lane >> 3);    // sblk>>3 multiple of 8
      GLDS16(A + (size_t)row * K_ + k0 + aCh * 8, &As[sblk * 8]);
    }
    // --- stage W: 128 rows x 64 f32 -> bf16, 2 granules/thread ---
    #pragma unroll
    for (int pass = 0; pass < 2; ++pass) {
      const int q   = pass * 512 + t;
      const int row = q >> 3, ch = q & 7;
      const float* wp = W + (size_t)(nBase + row) * K_ + k0 + ch * 8;
      const float4 a0 = *(const float4*)(wp);
      const float4 a1 = *(const float4*)(wp + 4);
      shortx8 bfv;
      bfv[0] = (short)f2bf(a0.x); bfv[1] = (short)f2bf(a0.y);
      bfv[2] = (short)f2bf(a0.z); bfv[3] = (short)f2bf(a0.w);
      bfv[4] = (short)f2bf(a1.x); bfv[5] = (short)f2bf(a1.y);
      bfv[6] = (short)f2bf(a1.z); bfv[7] = (short)f2bf(a1.w);
      *(shortx8*)(&Ws[(row * 8 + (ch ^ (row & 7))) * 8]) = bfv;
    }
    __syncthreads();

    // --- compute: 2 K-halves x 16 MFMA ---
    #pragma unroll
    for (int kh = 0; kh < 2; ++kh) {
      const int ch = kh * 4 + quad;
      shortx8 af[4], wf[4];
      #pragma unroll
      for (int ti = 0; ti < 4; ++ti) {
        const int row = wm + ti * 16 + lrow;
        af[ti] = *(const shortx8*)(&As[(row * 8 + (ch ^ rx)) * 8]);
      }
      #pragma unroll
      for (int tj = 0; tj < 4; ++tj) {
        const int row = wn + tj * 16 + lrow;
        wf[tj] = *(const shortx8*)(&Ws[(row * 8 + (ch ^ rx)) * 8]);
      }
      #pragma unroll
      for (int ti = 0; ti < 4; ++ti)
        #pragma unroll
        for (int tj = 0; tj < 4; ++tj)
          acc[ti][tj] = __builtin_amdgcn_mfma_f32_16x16x32_bf16(af[ti], wf[tj], acc[ti][tj], 0, 0, 0);
    }
    __syncthreads();
  }

  // epilogue: atomic accumulate (D layout: m = quad*4+reg, n = lane&15)
  #pragma unroll
  for (int ti = 0; ti < 4; ++ti)
    #pragma unroll
    for (int tj = 0; tj < 4; ++tj)
      #pragma unroll
      for (int j = 0; j < 4; ++j) {
        const int m = wm + ti * 16 + quad * 4 + j;           // mBase = 0
        const int n = nBase + wn + tj * 16 + lrow;
        atomicAdd(out + (size_t)m * OS_ + n, acc[ti][tj][j]);
      }
}

extern "C" void kernel_launch(void* const* d_in, const int* in_sizes, int n_in,
                              void* d_out, int out_size, void* d_ws, size_t ws_size,
                              hipStream_t stream) {
  const float* x        = (const float*)d_in[0];
  const int*   rxd_perm = (const int*)d_in[1];
  const int*   e_idx    = (const int*)d_in[2];
  const float* signs    = (const float*)d_in[3];
  const float* W        = (const float*)d_in[4];
  const float* bias     = (const float*)d_in[5];
  float* out = (float*)d_out;

  unsigned short* A = (unsigned short*)d_ws;   // 256 x 131072 bf16 = 67.1 MB

  build_A<<<dim3(B_ * C_ * R_), dim3(512), 0, stream>>>(x, rxd_perm, e_idx, signs, A);
  init_out<<<dim3((OS_ * M_) / 256), dim3(256), 0, stream>>>(bias, out);
  gemm_splitk<<<dim3(2 * ZZ), dim3(512), 0, stream>>>(A, W, out);
}